// Round 14
// baseline (191.888 us; speedup 1.0000x reference)
//
#include <hip/hip_runtime.h>
#include <hip/hip_bf16.h>

// CAM: out = (q @ k^T) @ v + v  ==  q @ (k^T @ v) + v.   S[b] = k^T v is 49x49.
// SINGLE fused kernel v2. R12 proved the grid barrier + co-residency works but
// died on atomic RMW contention (2.4M unsafeAtomicAdd) + scalar coherent loads.
// v2: contention-free cross-phase plumbing.
//   phase 1: ktv streaming MFMA (R8-proven). Partial S per (b,s) stored to a
//            PRIVATE ws slot via agent-scope relaxed stores (write-through, no
//            RMW, no sharing).
//   barrier: hand-rolled grid barrier (R12-proven). 1024 blocks = 4/CU x 256CU,
//            launch_bounds(256,4), LDS 23.5KB (cap 6/CU), VGPR ~40.
//   phase 2: R12-proven qs core. S = reduce of 8 partials via COALESCED
//            agent-scope loads (n-fastest => consecutive addrs) -> bf16 Sl LDS.
// Only the 4-byte counter is memset per replay.

#define BATCH 128
#define CH    1024
#define NN    49
#define GRID  1024
#define LDQT  56     // bf16 row stride of Qt: 112 B (16-mult)
#define LDST  72     // bf16 row stride of Sl : 144 B (16-mult)

typedef short  bf16x8 __attribute__((ext_vector_type(8)));
typedef float  f32x16 __attribute__((ext_vector_type(16)));

__device__ __forceinline__ short f2bf(float x) {
  return __builtin_bit_cast(short, __float2bfloat16(x));   // RNE
}

__global__ __launch_bounds__(256, 4) void cam_kernel(
    const float* __restrict__ Kg, const float* __restrict__ Vg,
    const float* __restrict__ Qg, float* __restrict__ Spart,
    unsigned* __restrict__ ctr, float* __restrict__ Og)
{
  const int tid  = threadIdx.x;
  const int wv   = tid >> 6;
  const int lane = tid & 63;
  const int g    = lane >> 5;
  const int ln   = lane & 31;
  const int i0   = (wv >> 1) * 32;
  const int j0   = (wv & 1)  * 32;
  const int b    = blockIdx.x >> 3;      // same batch mapping both phases
  const int s    = blockIdx.x & 7;

  __shared__ __align__(16) unsigned short Qt[128 * LDQT];  // 14.3 KB
  __shared__ __align__(16) unsigned short Sl[64 * LDST];   //  9.2 KB

  // ================= phase 1: Spart[b,s] = K-chunk^T @ V-chunk ==============
  {
    const int rowA = min(i0 + ln, NN - 1);   // clamp: dup loads, rows discarded
    const int rowB = min(j0 + ln, NN - 1);
    const size_t cbase = ((size_t)b * CH + (size_t)s * 128) * NN;
    const float* Ka = Kg + cbase + (size_t)(g * 8) * NN + rowA;
    const float* Vb = Vg + cbase + (size_t)(g * 8) * NN + rowB;

    f32x16 acc;
    #pragma unroll
    for (int r = 0; r < 16; ++r) acc[r] = 0.f;

    #pragma unroll 2
    for (int kc = 0; kc < 8; ++kc) {       // 8 chunks x 16 channels
      const float* ka = Ka + (size_t)kc * 16 * NN;
      const float* vb = Vb + (size_t)kc * 16 * NN;
      float kx[8], vx[8];
      #pragma unroll
      for (int e = 0; e < 8; ++e) { kx[e] = ka[e * NN]; vx[e] = vb[e * NN]; }
      bf16x8 ah, bh;
      #pragma unroll
      for (int e = 0; e < 8; ++e) { ah[e] = f2bf(kx[e]); bh[e] = f2bf(vx[e]); }
      acc = __builtin_amdgcn_mfma_f32_32x32x16_bf16(ah, bh, acc, 0, 0, 0);
    }

    // C/D: col(=j) = lane&31, row(=i) = (r&3)+8*(r>>2)+4*g   [m74/m101]
    const int j = j0 + ln;
    float* Sp = Spart + (size_t)blockIdx.x * (NN * NN);   // PRIVATE slot
    if (j < NN) {
      #pragma unroll
      for (int r = 0; r < 16; ++r) {
        const int i = i0 + (r & 3) + 8 * (r >> 2) + 4 * g;
        if (i < NN)
          __hip_atomic_store(&Sp[i * NN + j], acc[r],
                             __ATOMIC_RELAXED, __HIP_MEMORY_SCOPE_AGENT);
      }
    }
  }

  // ================= grid barrier (R12-proven) ==============================
  __syncthreads();                         // compiler drains vmcnt before bar
  if (tid == 0) {
    __threadfence();                       // device-scope release
    atomicAdd(ctr, 1u);
    while (__hip_atomic_load(ctr, __ATOMIC_ACQUIRE, __HIP_MEMORY_SCOPE_AGENT)
           < (unsigned)GRID)
      __builtin_amdgcn_s_sleep(2);
  }
  __syncthreads();

  // ================= phase 2: out[128-row tile] = q @ S + v =================
  {
    const int pr = s;                                  // 8 row-tiles per batch
    const size_t qbase = ((size_t)b * CH + (size_t)pr * 128) * NN;

    // stage 128 q-rows natural-layout bf16 (coalesced reads, linear writes)
    for (int f = tid; f < 128 * NN; f += 256) {
      const int r = f / NN, m = f - r * NN;
      Qt[r * LDQT + m] = (unsigned short)f2bf(Qg[qbase + f]);
    }
    // reduce 8 partials -> Sl[n][m] bf16 (coalesced agent loads: n fastest)
    {
      const float* sb = Spart + (size_t)(b * 8) * (NN * NN);
      for (int e = tid; e < 4096; e += 256) {
        const int m = e >> 6, n = e & 63;
        float v = 0.f;
        if (m < NN && n < NN) {
          const int off = m * NN + n;
          #pragma unroll
          for (int sp = 0; sp < 8; ++sp)
            v += __hip_atomic_load(&sb[(size_t)sp * (NN * NN) + off],
                                   __ATOMIC_RELAXED, __HIP_MEMORY_SCOPE_AGENT);
        }
        Sl[n * LDST + m] = (unsigned short)f2bf(v);    // zero-padded
      }
    }
    __syncthreads();

    const unsigned short* qt0 = &Qt[(i0 + ln) * LDQT];        // tile 0 row
    const unsigned short* qt1 = &Qt[(64 + i0 + ln) * LDQT];   // tile 1 row
    const unsigned short* slb = &Sl[(j0 + ln) * LDST];        // S^T row j

    f32x16 acc0, acc1;
    #pragma unroll
    for (int r = 0; r < 16; ++r) { acc0[r] = 0.f; acc1[r] = 0.f; }

    #pragma unroll
    for (int kc = 0; kc < 3; ++kc) {       // m0 <= 47: all fragment m's valid
      const int m0 = kc * 16 + g * 8;
      const bf16x8 a0 = *(const bf16x8*)&qt0[m0];    // one ds_read_b128
      const bf16x8 a1 = *(const bf16x8*)&qt1[m0];
      const bf16x8 bh = *(const bf16x8*)&slb[m0];
      acc0 = __builtin_amdgcn_mfma_f32_32x32x16_bf16(a0, bh, acc0, 0, 0, 0);
      acc1 = __builtin_amdgcn_mfma_f32_32x32x16_bf16(a1, bh, acc1, 0, 0, 0);
    }
    {                                      // tail: only m=48 real (R12-proven)
      const int m0 = 48 + g * 8;
      bf16x8 a0, a1;
      #pragma unroll
      for (int e = 0; e < 8; ++e) { a0[e] = 0; a1[e] = 0; }
      a0[0] = (g == 0) ? (short)qt0[48] : (short)0;
      a1[0] = (g == 0) ? (short)qt1[48] : (short)0;
      const bf16x8 bh = *(const bf16x8*)&slb[m0];    // zeros at m>=49
      acc0 = __builtin_amdgcn_mfma_f32_32x32x16_bf16(a0, bh, acc0, 0, 0, 0);
      acc1 = __builtin_amdgcn_mfma_f32_32x32x16_bf16(a1, bh, acc1, 0, 0, 0);
    }

    // epilogue: all 64 rows/tile valid; guard col j < 49; coalesced per r
    const int j = j0 + ln;
    if (j < NN) {
      #pragma unroll
      for (int r = 0; r < 16; ++r) {
        const int i = i0 + (r & 3) + 8 * (r >> 2) + 4 * g;
        const size_t o0 = qbase + (size_t)i * NN + j;
        const size_t o1 = qbase + (size_t)(64 + i) * NN + j;
        Og[o0] = acc0[r] + Vg[o0];
        Og[o1] = acc1[r] + Vg[o1];
      }
    }
  }
}

extern "C" void kernel_launch(void* const* d_in, const int* in_sizes, int n_in,
                              void* d_out, int out_size, void* d_ws, size_t ws_size,
                              hipStream_t stream) {
  (void)in_sizes; (void)n_in; (void)out_size; (void)ws_size;
  const float* v1 = (const float*)d_in[0];
  const float* q1 = (const float*)d_in[1];
  const float* k1 = (const float*)d_in[2];
  float* out = (float*)d_out;

  float*    spart = (float*)d_ws;                     // 1024*2401*4 = 9.83 MB
  unsigned* ctr   = (unsigned*)((char*)d_ws + (size_t)GRID * NN * NN * 4);

  hipMemsetAsync(ctr, 0, 256, stream);                // barrier counter only
  cam_kernel<<<dim3(GRID), dim3(256), 0, stream>>>(k1, v1, q1, spart, ctr, out);
}

// Round 15
// 35.757 us; speedup vs baseline: 5.3665x; 5.3665x over previous
//
#include <hip/hip_runtime.h>
#include <hip/hip_bf16.h>

// CAM: out = (q @ k^T) @ v + v  ==  q @ (k^T @ v) + v.   S[b] = k^T v is 49x49.
// TWO kernels (R15). R12/R14 proved single-kernel fusion dies on cross-XCD
// coherent traffic (~0.5 TB/s); R9 proved per-block scalar re-reduction dies.
//   ktv : streaming MFMA with SWAPPED operands (A=V, B=K) -> emits S^T
//         directly; row-major store is coalesced. No sred kernel needed.
//         split=4, padded [64][64] fp32 partials, junk stored unguarded.
//   qs  : inline float4 reduce of 4 partials -> bf16 Sl LDS (conflict-free),
//         natural-layout bf16 Qt, b128 A/B frags, R14 tail trick (junk S
//         cols m>=49 always multiply zero A slots), coalesced epilogue.

#define BATCH 128
#define CH    1024
#define NN    49
#define LDQT  56     // bf16 row stride of Qt: 112 B (16-mult)
#define LDST  72     // bf16 row stride of Sl : 144 B (16-mult)

typedef short  bf16x8 __attribute__((ext_vector_type(8)));
typedef float  f32x16 __attribute__((ext_vector_type(16)));

__device__ __forceinline__ short f2bf(float x) {
  return __builtin_bit_cast(short, __float2bfloat16(x));   // RNE
}

// -------- Kernel 1: Spart[b,s] = (V-chunk)^T-rows x (K-chunk) = S^T ---------
// D[a][c] = sum_ch V[ch][a] * K[ch][c] = S[c][a] = S^T[a][c]
__global__ __launch_bounds__(256) void ktv_kernel(
    const float* __restrict__ Kg, const float* __restrict__ Vg,
    float* __restrict__ Spart) {
  const int blk  = blockIdx.x;           // 512 = 128 batches x 4 splits
  const int b    = blk >> 2;
  const int s    = blk & 3;
  const int tid  = threadIdx.x;
  const int wv   = tid >> 6;
  const int lane = tid & 63;
  const int g    = lane >> 5;
  const int ln   = lane & 31;
  const int i0   = (wv >> 1) * 32;       // S^T row quadrant (V position)
  const int j0   = (wv & 1)  * 32;       // S^T col quadrant (K position)
  const int rowA = min(i0 + ln, NN - 1); // clamp: dup loads, junk discarded
  const int rowB = min(j0 + ln, NN - 1);

  const size_t cbase = ((size_t)b * CH + (size_t)s * 256) * NN;
  const float* Va = Vg + cbase + (size_t)(g * 8) * NN + rowA;   // A = V
  const float* Kb = Kg + cbase + (size_t)(g * 8) * NN + rowB;   // B = K

  f32x16 acc;
  #pragma unroll
  for (int r = 0; r < 16; ++r) acc[r] = 0.f;

  #pragma unroll 2
  for (int kc = 0; kc < 16; ++kc) {      // 16 chunks x 16 channels = 256 ch
    const float* va = Va + (size_t)kc * 16 * NN;
    const float* kb = Kb + (size_t)kc * 16 * NN;
    float vx[8], kx[8];
    #pragma unroll
    for (int e = 0; e < 8; ++e) { vx[e] = va[e * NN]; kx[e] = kb[e * NN]; }
    bf16x8 av, bk;
    #pragma unroll
    for (int e = 0; e < 8; ++e) { av[e] = f2bf(vx[e]); bk[e] = f2bf(kx[e]); }
    acc = __builtin_amdgcn_mfma_f32_32x32x16_bf16(av, bk, acc, 0, 0, 0);
  }

  // C/D: col = lane&31, row = (r&3)+8*(r>>2)+4*g  [m74/m101, R7/R8-validated]
  // store S^T[a][c] row-major [64][64]: coalesced, junk rows/cols included
  float* Sp = Spart + (size_t)blk * 4096;
  const int c = j0 + ln;
  #pragma unroll
  for (int r = 0; r < 16; ++r) {
    const int a = i0 + (r & 3) + 8 * (r >> 2) + 4 * g;
    Sp[a * 64 + c] = acc[r];
  }
}

// -------- Kernel 2: out[128-row tile] = q @ S + v ---------------------------
__global__ __launch_bounds__(256) void qs_kernel(
    const float* __restrict__ Qg, const float* __restrict__ Vg,
    const float* __restrict__ Spart, float* __restrict__ Og) {
  const int blk  = blockIdx.x;           // 1024 = 128 batches x 8 row-tiles
  const int b    = blk >> 3;
  const int pr   = blk & 7;
  const int tid  = threadIdx.x;
  const int wv   = tid >> 6;
  const int lane = tid & 63;
  const int g    = lane >> 5;
  const int ln   = lane & 31;
  const int i0   = (wv >> 1) * 32;
  const int j0   = (wv & 1)  * 32;

  __shared__ __align__(16) unsigned short Qt[128 * LDQT];  // 14.3 KB
  __shared__ __align__(16) unsigned short Sl[64 * LDST];   //  9.2 KB

  const size_t qbase = ((size_t)b * CH + (size_t)pr * 128) * NN;

  // stage 128 q-rows natural-layout bf16 (coalesced reads, linear writes)
  for (int f = tid; f < 128 * NN; f += 256) {
    const int r = f / NN, m = f - r * NN;
    Qt[r * LDQT + m] = (unsigned short)f2bf(Qg[qbase + f]);
  }

  // reduce 4 partials -> Sl[n][m] bf16; float4 coalesced reads, row writes
  {
    const float* sp = Spart + (size_t)(b * 4) * 4096;
    for (int e4 = tid; e4 < 1024; e4 += 256) {
      float4 v = *(const float4*)&sp[4 * e4];
      #pragma unroll
      for (int s = 1; s < 4; ++s) {
        const float4 w = *(const float4*)&sp[(size_t)s * 4096 + 4 * e4];
        v.x += w.x; v.y += w.y; v.z += w.z; v.w += w.w;
      }
      const int n = e4 >> 4, m = (e4 & 15) * 4;
      ushort4 o;
      o.x = (unsigned short)f2bf(v.x); o.y = (unsigned short)f2bf(v.y);
      o.z = (unsigned short)f2bf(v.z); o.w = (unsigned short)f2bf(v.w);
      *(ushort4*)&Sl[n * LDST + m] = o;        // 8-B aligned, conflict-free
    }
  }
  __syncthreads();

  const unsigned short* qt0 = &Qt[(i0 + ln) * LDQT];        // tile 0 row
  const unsigned short* qt1 = &Qt[(64 + i0 + ln) * LDQT];   // tile 1 row
  const unsigned short* slb = &Sl[(j0 + ln) * LDST];        // S^T row j

  f32x16 acc0, acc1;
  #pragma unroll
  for (int r = 0; r < 16; ++r) { acc0[r] = 0.f; acc1[r] = 0.f; }

  #pragma unroll
  for (int kc = 0; kc < 3; ++kc) {       // m0 <= 47: all fragment m's valid
    const int m0 = kc * 16 + g * 8;
    const bf16x8 a0 = *(const bf16x8*)&qt0[m0];    // one ds_read_b128
    const bf16x8 a1 = *(const bf16x8*)&qt1[m0];
    const bf16x8 bh = *(const bf16x8*)&slb[m0];
    acc0 = __builtin_amdgcn_mfma_f32_32x32x16_bf16(a0, bh, acc0, 0, 0, 0);
    acc1 = __builtin_amdgcn_mfma_f32_32x32x16_bf16(a1, bh, acc1, 0, 0, 0);
  }
  {                                      // tail: only m=48 real (R14-proven)
    const int m0 = 48 + g * 8;
    bf16x8 a0, a1;
    #pragma unroll
    for (int e = 0; e < 8; ++e) { a0[e] = 0; a1[e] = 0; }
    a0[0] = (g == 0) ? (short)qt0[48] : (short)0;
    a1[0] = (g == 0) ? (short)qt1[48] : (short)0;
    const bf16x8 bh = *(const bf16x8*)&slb[m0];    // junk x zero-A = harmless
    acc0 = __builtin_amdgcn_mfma_f32_32x32x16_bf16(a0, bh, acc0, 0, 0, 0);
    acc1 = __builtin_amdgcn_mfma_f32_32x32x16_bf16(a1, bh, acc1, 0, 0, 0);
  }

  // epilogue: all 64 rows/tile valid; guard col j < 49; coalesced per r
  const int j = j0 + ln;
  if (j < NN) {
    #pragma unroll
    for (int r = 0; r < 16; ++r) {
      const int i = i0 + (r & 3) + 8 * (r >> 2) + 4 * g;
      const size_t o0 = qbase + (size_t)i * NN + j;
      const size_t o1 = qbase + (size_t)(64 + i) * NN + j;
      Og[o0] = acc0[r] + Vg[o0];
      Og[o1] = acc1[r] + Vg[o1];
    }
  }
}

extern "C" void kernel_launch(void* const* d_in, const int* in_sizes, int n_in,
                              void* d_out, int out_size, void* d_ws, size_t ws_size,
                              hipStream_t stream) {
  (void)in_sizes; (void)n_in; (void)out_size; (void)ws_size;
  const float* v1 = (const float*)d_in[0];
  const float* q1 = (const float*)d_in[1];
  const float* k1 = (const float*)d_in[2];
  float* out = (float*)d_out;

  float* spart = (float*)d_ws;           // 512 * 4096 * 4 = 8.39 MB

  ktv_kernel<<<dim3(BATCH * 4), dim3(256), 0, stream>>>(k1, v1, spart);
  qs_kernel<<<dim3(BATCH * 8), dim3(256), 0, stream>>>(q1, v1, spart, out);
}

// Round 16
// 35.031 us; speedup vs baseline: 5.4776x; 1.0207x over previous
//
#include <hip/hip_runtime.h>
#include <hip/hip_bf16.h>

// CAM: out = (q @ k^T) @ v + v  ==  q @ (k^T @ v) + v.   S[b] = k^T v is 49x49.
// TWO kernels (R16 = R15 + occupancy & traffic tuning):
//   ktv : streaming MFMA, swapped operands (A=V,B=K) -> emits S^T directly.
//         split=8 (1024 blocks = 4/CU; R15's 512 = 2/CU was latency-limited),
//         partials stored BF16 (halves the S round-trip traffic).
//   qs  : R15-proven core. Reduce 8 bf16 partials (ushort8 coalesced loads,
//         fp32 accumulate) -> Sl LDS; natural-layout bf16 Qt; b128 A/B frags;
//         tail trick (junk S cols m>=49 multiply zeroed A slots); coalesced
//         epilogue out = acc + v.
// Fusion is a dead end (R12/R14: cross-XCD coherent path ~0.5 TB/s).

#define BATCH 128
#define CH    1024
#define NN    49
#define SPLIT 8
#define LDQT  56     // bf16 row stride of Qt: 112 B (16-mult)
#define LDST  72     // bf16 row stride of Sl : 144 B (16-mult)

typedef short  bf16x8 __attribute__((ext_vector_type(8)));
typedef float  f32x16 __attribute__((ext_vector_type(16)));
typedef unsigned short u16x8 __attribute__((ext_vector_type(8)));

__device__ __forceinline__ short f2bf(float x) {
  return __builtin_bit_cast(short, __float2bfloat16(x));   // RNE
}
__device__ __forceinline__ float bf2f(unsigned short h) {
  return __builtin_bit_cast(float, ((unsigned)h) << 16);
}

// -------- Kernel 1: Spart[b,s] = bf16( V-chunk^T x K-chunk ) = S^T-part -----
// D[a][c] = sum_ch V[ch][a] * K[ch][c] = S^T[a][c]; row-major [64][64] store.
__global__ __launch_bounds__(256) void ktv_kernel(
    const float* __restrict__ Kg, const float* __restrict__ Vg,
    unsigned short* __restrict__ Spart) {
  const int blk  = blockIdx.x;           // 1024 = 128 batches x 8 splits
  const int b    = blk >> 3;
  const int s    = blk & 7;
  const int tid  = threadIdx.x;
  const int wv   = tid >> 6;
  const int lane = tid & 63;
  const int g    = lane >> 5;
  const int ln   = lane & 31;
  const int i0   = (wv >> 1) * 32;       // S^T row quadrant (V position)
  const int j0   = (wv & 1)  * 32;       // S^T col quadrant (K position)
  const int rowA = min(i0 + ln, NN - 1); // clamp: dup loads, junk discarded
  const int rowB = min(j0 + ln, NN - 1);

  const size_t cbase = ((size_t)b * CH + (size_t)s * 128) * NN;
  const float* Va = Vg + cbase + (size_t)(g * 8) * NN + rowA;   // A = V
  const float* Kb = Kg + cbase + (size_t)(g * 8) * NN + rowB;   // B = K

  f32x16 acc;
  #pragma unroll
  for (int r = 0; r < 16; ++r) acc[r] = 0.f;

  #pragma unroll 4
  for (int kc = 0; kc < 8; ++kc) {       // 8 chunks x 16 channels = 128 ch
    const float* va = Va + (size_t)kc * 16 * NN;
    const float* kb = Kb + (size_t)kc * 16 * NN;
    float vx[8], kx[8];
    #pragma unroll
    for (int e = 0; e < 8; ++e) { vx[e] = va[e * NN]; kx[e] = kb[e * NN]; }
    bf16x8 av, bk;
    #pragma unroll
    for (int e = 0; e < 8; ++e) { av[e] = f2bf(vx[e]); bk[e] = f2bf(kx[e]); }
    acc = __builtin_amdgcn_mfma_f32_32x32x16_bf16(av, bk, acc, 0, 0, 0);
  }

  // C/D: col = lane&31, row = (r&3)+8*(r>>2)+4*g  [m74/m101, HW-validated]
  unsigned short* Sp = Spart + (size_t)blk * 4096;
  const int c = j0 + ln;
  #pragma unroll
  for (int r = 0; r < 16; ++r) {
    const int a = i0 + (r & 3) + 8 * (r >> 2) + 4 * g;
    Sp[a * 64 + c] = (unsigned short)f2bf(acc[r]);
  }
}

// -------- Kernel 2: out[128-row tile] = q @ S + v ---------------------------
__global__ __launch_bounds__(256) void qs_kernel(
    const float* __restrict__ Qg, const float* __restrict__ Vg,
    const unsigned short* __restrict__ Spart, float* __restrict__ Og) {
  const int blk  = blockIdx.x;           // 1024 = 128 batches x 8 row-tiles
  const int b    = blk >> 3;
  const int pr   = blk & 7;
  const int tid  = threadIdx.x;
  const int wv   = tid >> 6;
  const int lane = tid & 63;
  const int g    = lane >> 5;
  const int ln   = lane & 31;
  const int i0   = (wv >> 1) * 32;
  const int j0   = (wv & 1)  * 32;

  __shared__ __align__(16) unsigned short Qt[128 * LDQT];  // 14.3 KB
  __shared__ __align__(16) unsigned short Sl[64 * LDST];   //  9.2 KB

  const size_t qbase = ((size_t)b * CH + (size_t)pr * 128) * NN;

  // stage 128 q-rows natural-layout bf16 (coalesced reads, linear writes)
  for (int f = tid; f < 128 * NN; f += 256) {
    const int r = f / NN, m = f - r * NN;
    Qt[r * LDQT + m] = (unsigned short)f2bf(Qg[qbase + f]);
  }

  // reduce 8 bf16 partials -> Sl[n][m]; ushort8 coalesced loads, fp32 sum
  {
    const unsigned short* sp = Spart + (size_t)(b * SPLIT) * 4096;
    for (int e8 = tid; e8 < 512; e8 += 256) {
      float v[8];
      #pragma unroll
      for (int k = 0; k < 8; ++k) v[k] = 0.f;
      #pragma unroll
      for (int s = 0; s < SPLIT; ++s) {
        const u16x8 w = *(const u16x8*)&sp[(size_t)s * 4096 + 8 * e8];
        #pragma unroll
        for (int k = 0; k < 8; ++k) v[k] += bf2f(w[k]);
      }
      const int n = e8 >> 3, m0 = (e8 & 7) * 8;
      u16x8 o;
      #pragma unroll
      for (int k = 0; k < 8; ++k) o[k] = (unsigned short)f2bf(v[k]);
      *(u16x8*)&Sl[n * LDST + m0] = o;       // 16-B aligned, conflict-light
    }
  }
  __syncthreads();

  const unsigned short* qt0 = &Qt[(i0 + ln) * LDQT];        // tile 0 row
  const unsigned short* qt1 = &Qt[(64 + i0 + ln) * LDQT];   // tile 1 row
  const unsigned short* slb = &Sl[(j0 + ln) * LDST];        // S^T row j

  f32x16 acc0, acc1;
  #pragma unroll
  for (int r = 0; r < 16; ++r) { acc0[r] = 0.f; acc1[r] = 0.f; }

  #pragma unroll
  for (int kc = 0; kc < 3; ++kc) {       // m0 <= 47: all fragment m's valid
    const int m0 = kc * 16 + g * 8;
    const bf16x8 a0 = *(const bf16x8*)&qt0[m0];    // one ds_read_b128
    const bf16x8 a1 = *(const bf16x8*)&qt1[m0];
    const bf16x8 bh = *(const bf16x8*)&slb[m0];
    acc0 = __builtin_amdgcn_mfma_f32_32x32x16_bf16(a0, bh, acc0, 0, 0, 0);
    acc1 = __builtin_amdgcn_mfma_f32_32x32x16_bf16(a1, bh, acc1, 0, 0, 0);
  }
  {                                      // tail: only m=48 real (R14-proven)
    const int m0 = 48 + g * 8;
    bf16x8 a0, a1;
    #pragma unroll
    for (int e = 0; e < 8; ++e) { a0[e] = 0; a1[e] = 0; }
    a0[0] = (g == 0) ? (short)qt0[48] : (short)0;
    a1[0] = (g == 0) ? (short)qt1[48] : (short)0;
    const bf16x8 bh = *(const bf16x8*)&slb[m0];    // junk x zero-A = harmless
    acc0 = __builtin_amdgcn_mfma_f32_32x32x16_bf16(a0, bh, acc0, 0, 0, 0);
    acc1 = __builtin_amdgcn_mfma_f32_32x32x16_bf16(a1, bh, acc1, 0, 0, 0);
  }

  // epilogue: all 64 rows/tile valid; guard col j < 49; coalesced per r
  const int j = j0 + ln;
  if (j < NN) {
    #pragma unroll
    for (int r = 0; r < 16; ++r) {
      const int i = i0 + (r & 3) + 8 * (r >> 2) + 4 * g;
      const size_t o0 = qbase + (size_t)i * NN + j;
      const size_t o1 = qbase + (size_t)(64 + i) * NN + j;
      Og[o0] = acc0[r] + Vg[o0];
      Og[o1] = acc1[r] + Vg[o1];
    }
  }
}

extern "C" void kernel_launch(void* const* d_in, const int* in_sizes, int n_in,
                              void* d_out, int out_size, void* d_ws, size_t ws_size,
                              hipStream_t stream) {
  (void)in_sizes; (void)n_in; (void)out_size; (void)ws_size;
  const float* v1 = (const float*)d_in[0];
  const float* q1 = (const float*)d_in[1];
  const float* k1 = (const float*)d_in[2];
  float* out = (float*)d_out;

  unsigned short* spart = (unsigned short*)d_ws;   // 1024 * 4096 * 2 = 8.39 MB

  ktv_kernel<<<dim3(BATCH * SPLIT), dim3(256), 0, stream>>>(k1, v1, spart);
  qs_kernel<<<dim3(BATCH * 8), dim3(256), 0, stream>>>(q1, v1, spart, out);
}

// Round 17
// 29.096 us; speedup vs baseline: 6.5949x; 1.2040x over previous
//
#include <hip/hip_runtime.h>
#include <hip/hip_bf16.h>

// CAM: out = (q @ k^T) @ v + v  ==  q @ (k^T @ v) + v.   S[b] = k^T v is 49x49.
// TWO kernels (R17 = R16 + batch->XCD affinity swizzle):
//   Both grids are 1024 blocks; swizzle wgid=(orig%8)*128+orig/8 is bijective
//   (1024%8==0) and lands all 8 blocks of a batch on ONE XCD: qs's 8x-redundant
//   64KB Spart reduce then hits that XCD's L2 instead of pulling 8 copies
//   from L3 (-57 MB interconnect traffic).
//   ktv : streaming MFMA, swapped operands (A=V,B=K) -> emits S^T directly,
//         bf16 [64][64] partials, split=8. (R16-proven)
//   qs  : reduce 8 bf16 partials (u16x8 coalesced, fp32 sum) -> Sl LDS;
//         natural-layout bf16 Qt; b128 A/B frags; zero-A tail; coalesced
//         epilogue out = acc + v. (R15/R16-proven)
// Fusion is a dead end (R12/R14: cross-XCD coherent path ~0.5 TB/s).

#define BATCH 128
#define CH    1024
#define NN    49
#define SPLIT 8
#define LDQT  56     // bf16 row stride of Qt: 112 B (16-mult)
#define LDST  72     // bf16 row stride of Sl : 144 B (16-mult)

typedef short  bf16x8 __attribute__((ext_vector_type(8)));
typedef float  f32x16 __attribute__((ext_vector_type(16)));
typedef unsigned short u16x8 __attribute__((ext_vector_type(8)));

__device__ __forceinline__ short f2bf(float x) {
  return __builtin_bit_cast(short, __float2bfloat16(x));   // RNE
}
__device__ __forceinline__ float bf2f(unsigned short h) {
  return __builtin_bit_cast(float, ((unsigned)h) << 16);
}
// bijective for 1024 blocks: consecutive orig (same batch) -> same XCD slot
__device__ __forceinline__ int xcd_swizzle(int wgid) {
  return (wgid & 7) * 128 + (wgid >> 3);   // orig = inverse mapping
}

// -------- Kernel 1: Spart[b,s] = bf16( V-chunk^T x K-chunk ) = S^T-part -----
// D[a][c] = sum_ch V[ch][a] * K[ch][c] = S^T[a][c]; row-major [64][64] store.
__global__ __launch_bounds__(256) void ktv_kernel(
    const float* __restrict__ Kg, const float* __restrict__ Vg,
    unsigned short* __restrict__ Spart) {
  const int blk  = xcd_swizzle(blockIdx.x);  // 1024 = 128 batches x 8 splits
  const int b    = blk >> 3;
  const int s    = blk & 7;
  const int tid  = threadIdx.x;
  const int wv   = tid >> 6;
  const int lane = tid & 63;
  const int g    = lane >> 5;
  const int ln   = lane & 31;
  const int i0   = (wv >> 1) * 32;       // S^T row quadrant (V position)
  const int j0   = (wv & 1)  * 32;       // S^T col quadrant (K position)
  const int rowA = min(i0 + ln, NN - 1); // clamp: dup loads, junk discarded
  const int rowB = min(j0 + ln, NN - 1);

  const size_t cbase = ((size_t)b * CH + (size_t)s * 128) * NN;
  const float* Va = Vg + cbase + (size_t)(g * 8) * NN + rowA;   // A = V
  const float* Kb = Kg + cbase + (size_t)(g * 8) * NN + rowB;   // B = K

  f32x16 acc;
  #pragma unroll
  for (int r = 0; r < 16; ++r) acc[r] = 0.f;

  #pragma unroll 4
  for (int kc = 0; kc < 8; ++kc) {       // 8 chunks x 16 channels = 128 ch
    const float* va = Va + (size_t)kc * 16 * NN;
    const float* kb = Kb + (size_t)kc * 16 * NN;
    float vx[8], kx[8];
    #pragma unroll
    for (int e = 0; e < 8; ++e) { vx[e] = va[e * NN]; kx[e] = kb[e * NN]; }
    bf16x8 av, bk;
    #pragma unroll
    for (int e = 0; e < 8; ++e) { av[e] = f2bf(vx[e]); bk[e] = f2bf(kx[e]); }
    acc = __builtin_amdgcn_mfma_f32_32x32x16_bf16(av, bk, acc, 0, 0, 0);
  }

  // C/D: col = lane&31, row = (r&3)+8*(r>>2)+4*g  [m74/m101, HW-validated]
  unsigned short* Sp = Spart + (size_t)blk * 4096;
  const int c = j0 + ln;
  #pragma unroll
  for (int r = 0; r < 16; ++r) {
    const int a = i0 + (r & 3) + 8 * (r >> 2) + 4 * g;
    Sp[a * 64 + c] = (unsigned short)f2bf(acc[r]);
  }
}

// -------- Kernel 2: out[128-row tile] = q @ S + v ---------------------------
__global__ __launch_bounds__(256) void qs_kernel(
    const float* __restrict__ Qg, const float* __restrict__ Vg,
    const unsigned short* __restrict__ Spart, float* __restrict__ Og) {
  const int blk  = xcd_swizzle(blockIdx.x);  // 1024 = 128 batches x 8 tiles
  const int b    = blk >> 3;
  const int pr   = blk & 7;
  const int tid  = threadIdx.x;
  const int wv   = tid >> 6;
  const int lane = tid & 63;
  const int g    = lane >> 5;
  const int ln   = lane & 31;
  const int i0   = (wv >> 1) * 32;
  const int j0   = (wv & 1)  * 32;

  __shared__ __align__(16) unsigned short Qt[128 * LDQT];  // 14.3 KB
  __shared__ __align__(16) unsigned short Sl[64 * LDST];   //  9.2 KB

  const size_t qbase = ((size_t)b * CH + (size_t)pr * 128) * NN;

  // stage 128 q-rows natural-layout bf16 (coalesced reads, linear writes)
  for (int f = tid; f < 128 * NN; f += 256) {
    const int r = f / NN, m = f - r * NN;
    Qt[r * LDQT + m] = (unsigned short)f2bf(Qg[qbase + f]);
  }

  // reduce 8 bf16 partials -> Sl[n][m]; u16x8 coalesced loads (L2-hot via
  // same-XCD swizzle), fp32 accumulate
  {
    const unsigned short* sp = Spart + (size_t)(b * SPLIT) * 4096;
    for (int e8 = tid; e8 < 512; e8 += 256) {
      float v[8];
      #pragma unroll
      for (int k = 0; k < 8; ++k) v[k] = 0.f;
      #pragma unroll
      for (int s = 0; s < SPLIT; ++s) {
        const u16x8 w = *(const u16x8*)&sp[(size_t)s * 4096 + 8 * e8];
        #pragma unroll
        for (int k = 0; k < 8; ++k) v[k] += bf2f(w[k]);
      }
      const int n = e8 >> 3, m0 = (e8 & 7) * 8;
      u16x8 o;
      #pragma unroll
      for (int k = 0; k < 8; ++k) o[k] = (unsigned short)f2bf(v[k]);
      *(u16x8*)&Sl[n * LDST + m0] = o;       // 16-B aligned, conflict-light
    }
  }
  __syncthreads();

  const unsigned short* qt0 = &Qt[(i0 + ln) * LDQT];        // tile 0 row
  const unsigned short* qt1 = &Qt[(64 + i0 + ln) * LDQT];   // tile 1 row
  const unsigned short* slb = &Sl[(j0 + ln) * LDST];        // S^T row j

  f32x16 acc0, acc1;
  #pragma unroll
  for (int r = 0; r < 16; ++r) { acc0[r] = 0.f; acc1[r] = 0.f; }

  #pragma unroll
  for (int kc = 0; kc < 3; ++kc) {       // m0 <= 47: all fragment m's valid
    const int m0 = kc * 16 + g * 8;
    const bf16x8 a0 = *(const bf16x8*)&qt0[m0];    // one ds_read_b128
    const bf16x8 a1 = *(const bf16x8*)&qt1[m0];
    const bf16x8 bh = *(const bf16x8*)&slb[m0];
    acc0 = __builtin_amdgcn_mfma_f32_32x32x16_bf16(a0, bh, acc0, 0, 0, 0);
    acc1 = __builtin_amdgcn_mfma_f32_32x32x16_bf16(a1, bh, acc1, 0, 0, 0);
  }
  {                                      // tail: only m=48 real (R14-proven)
    const int m0 = 48 + g * 8;
    bf16x8 a0, a1;
    #pragma unroll
    for (int e = 0; e < 8; ++e) { a0[e] = 0; a1[e] = 0; }
    a0[0] = (g == 0) ? (short)qt0[48] : (short)0;
    a1[0] = (g == 0) ? (short)qt1[48] : (short)0;
    const bf16x8 bh = *(const bf16x8*)&slb[m0];    // junk x zero-A = harmless
    acc0 = __builtin_amdgcn_mfma_f32_32x32x16_bf16(a0, bh, acc0, 0, 0, 0);
    acc1 = __builtin_amdgcn_mfma_f32_32x32x16_bf16(a1, bh, acc1, 0, 0, 0);
  }

  // epilogue: all 64 rows/tile valid; guard col j < 49; coalesced per r
  const int j = j0 + ln;
  if (j < NN) {
    #pragma unroll
    for (int r = 0; r < 16; ++r) {
      const int i = i0 + (r & 3) + 8 * (r >> 2) + 4 * g;
      const size_t o0 = qbase + (size_t)i * NN + j;
      const size_t o1 = qbase + (size_t)(64 + i) * NN + j;
      Og[o0] = acc0[r] + Vg[o0];
      Og[o1] = acc1[r] + Vg[o1];
    }
  }
}

extern "C" void kernel_launch(void* const* d_in, const int* in_sizes, int n_in,
                              void* d_out, int out_size, void* d_ws, size_t ws_size,
                              hipStream_t stream) {
  (void)in_sizes; (void)n_in; (void)out_size; (void)ws_size;
  const float* v1 = (const float*)d_in[0];
  const float* q1 = (const float*)d_in[1];
  const float* k1 = (const float*)d_in[2];
  float* out = (float*)d_out;

  unsigned short* spart = (unsigned short*)d_ws;   // 1024 * 4096 * 2 = 8.39 MB

  ktv_kernel<<<dim3(BATCH * SPLIT), dim3(256), 0, stream>>>(k1, v1, spart);
  qs_kernel<<<dim3(BATCH * 8), dim3(256), 0, stream>>>(q1, v1, spart, out);
}

// Round 18
// 28.184 us; speedup vs baseline: 6.8083x; 1.0324x over previous
//
#include <hip/hip_runtime.h>
#include <hip/hip_bf16.h>

// CAM: out = (q @ k^T) @ v + v  ==  q @ (k^T @ v) + v.   S[b] = k^T v is 49x49.
// TWO kernels (R18 = R17 + traffic/instruction micro-opts):
//   ktv : streaming MFMA (A=V,B=K -> S^T direct), split=8, batch->XCD swizzle.
//         NEW: Spart shrunk to bf16 [49][64] (junk rows dropped, -23% S
//         traffic) and stored via LDS bounce -> flat u16x8 (1KB/wave stores).
//   qs  : R17-proven core. NEW: Q staged via float4 loads (4x fewer instrs);
//         reduce covers 392 u16x8 (49 rows). Junk cols c>=49 stay finite
//         (clamped dup data) so the zero-A tail stays exact; Sl rows n>=49
//         uninitialized -> only feed discarded j>=49 outputs.
// Fusion dead (R12/R14: cross-XCD coherent ~0.5 TB/s). Swizzle proven (R17).

#define BATCH 128
#define CH    1024
#define NN    49
#define SPLIT 8
#define SROW  64                 // Spart cols per row
#define SSZ   (NN * SROW)        // 3136 u16 = 6272 B per partial (16-mult)
#define LDQT  56                 // bf16 row stride of Qt: 112 B
#define LDST  72                 // bf16 row stride of Sl : 144 B

typedef short  bf16x8 __attribute__((ext_vector_type(8)));
typedef float  f32x16 __attribute__((ext_vector_type(16)));
typedef unsigned short u16x8 __attribute__((ext_vector_type(8)));

__device__ __forceinline__ short f2bf(float x) {
  return __builtin_bit_cast(short, __float2bfloat16(x));   // RNE
}
__device__ __forceinline__ float bf2f(unsigned short h) {
  return __builtin_bit_cast(float, ((unsigned)h) << 16);
}
// bijective for 1024 blocks; all 8 blocks of a batch share one XCD (R17)
__device__ __forceinline__ int xcd_swizzle(int wgid) {
  return (wgid & 7) * 128 + (wgid >> 3);
}

// -------- Kernel 1: Spart[b,s] = bf16( V-chunk^T x K-chunk ) = S^T-part -----
__global__ __launch_bounds__(256) void ktv_kernel(
    const float* __restrict__ Kg, const float* __restrict__ Vg,
    unsigned short* __restrict__ Spart) {
  const int blk  = xcd_swizzle(blockIdx.x);  // 1024 = 128 batches x 8 splits
  const int b    = blk >> 3;
  const int s    = blk & 7;
  const int tid  = threadIdx.x;
  const int wv   = tid >> 6;
  const int lane = tid & 63;
  const int g    = lane >> 5;
  const int ln   = lane & 31;
  const int i0   = (wv >> 1) * 32;       // S^T row quadrant (V position)
  const int j0   = (wv & 1)  * 32;       // S^T col quadrant (K position)
  const int rowA = min(i0 + ln, NN - 1); // clamp: dup loads, junk discarded
  const int rowB = min(j0 + ln, NN - 1);

  __shared__ __align__(16) unsigned short Ot[SSZ];   // 6.3 KB bounce tile

  const size_t cbase = ((size_t)b * CH + (size_t)s * 128) * NN;
  const float* Va = Vg + cbase + (size_t)(g * 8) * NN + rowA;   // A = V
  const float* Kb = Kg + cbase + (size_t)(g * 8) * NN + rowB;   // B = K

  f32x16 acc;
  #pragma unroll
  for (int r = 0; r < 16; ++r) acc[r] = 0.f;

  #pragma unroll 4
  for (int kc = 0; kc < 8; ++kc) {       // 8 chunks x 16 channels = 128 ch
    const float* va = Va + (size_t)kc * 16 * NN;
    const float* kb = Kb + (size_t)kc * 16 * NN;
    float vx[8], kx[8];
    #pragma unroll
    for (int e = 0; e < 8; ++e) { vx[e] = va[e * NN]; kx[e] = kb[e * NN]; }
    bf16x8 av, bk;
    #pragma unroll
    for (int e = 0; e < 8; ++e) { av[e] = f2bf(vx[e]); bk[e] = f2bf(kx[e]); }
    acc = __builtin_amdgcn_mfma_f32_32x32x16_bf16(av, bk, acc, 0, 0, 0);
  }

  // C/D: col = lane&31, row = (r&3)+8*(r>>2)+4*g  [m74/m101, HW-validated]
  const int c = j0 + ln;
  #pragma unroll
  for (int r = 0; r < 16; ++r) {
    const int a = i0 + (r & 3) + 8 * (r >> 2) + 4 * g;
    if (a < NN) Ot[a * SROW + c] = (unsigned short)f2bf(acc[r]);  // 2-way ok
  }
  __syncthreads();

  // flat u16x8 stores: 1 KB/wave/instr, ~1.5 instr/thread
  unsigned short* Sp = Spart + (size_t)blk * SSZ;
  for (int e8 = tid; e8 < SSZ / 8; e8 += 256)
    *(u16x8*)&Sp[8 * e8] = *(const u16x8*)&Ot[8 * e8];
}

// -------- Kernel 2: out[128-row tile] = q @ S + v ---------------------------
__global__ __launch_bounds__(256) void qs_kernel(
    const float* __restrict__ Qg, const float* __restrict__ Vg,
    const unsigned short* __restrict__ Spart, float* __restrict__ Og) {
  const int blk  = xcd_swizzle(blockIdx.x);  // 1024 = 128 batches x 8 tiles
  const int b    = blk >> 3;
  const int pr   = blk & 7;
  const int tid  = threadIdx.x;
  const int wv   = tid >> 6;
  const int lane = tid & 63;
  const int g    = lane >> 5;
  const int ln   = lane & 31;
  const int i0   = (wv >> 1) * 32;
  const int j0   = (wv & 1)  * 32;

  __shared__ __align__(16) unsigned short Qt[128 * LDQT];  // 14.3 KB
  __shared__ __align__(16) unsigned short Sl[64 * LDST];   //  9.2 KB

  const size_t qbase = ((size_t)b * CH + (size_t)pr * 128) * NN;

  // stage 128 q-rows bf16 via float4 loads (16-B aligned; 1 KB/wave/instr)
  for (int fq = tid; fq < 128 * NN / 4; fq += 256) {
    const float4 qv = *(const float4*)&Qg[qbase + 4 * fq];
    const int f0 = 4 * fq;
    #pragma unroll
    for (int k = 0; k < 4; ++k) {
      const int f = f0 + k;
      const int r = f / NN, m = f - r * NN;
      Qt[r * LDQT + m] = (unsigned short)f2bf(((const float*)&qv)[k]);
    }
  }

  // reduce 8 bf16 partials -> Sl[n][m], n<49 (rows 49-63 unused->discarded js)
  {
    const unsigned short* sp = Spart + (size_t)(b * SPLIT) * SSZ;
    for (int e8 = tid; e8 < SSZ / 8; e8 += 256) {
      float v[8];
      #pragma unroll
      for (int k = 0; k < 8; ++k) v[k] = 0.f;
      #pragma unroll
      for (int s = 0; s < SPLIT; ++s) {
        const u16x8 w = *(const u16x8*)&sp[(size_t)s * SSZ + 8 * e8];
        #pragma unroll
        for (int k = 0; k < 8; ++k) v[k] += bf2f(w[k]);
      }
      const int n = e8 >> 3, m0 = (e8 & 7) * 8;   // n in 0..48, m0 in 0..56
      u16x8 o;
      #pragma unroll
      for (int k = 0; k < 8; ++k) o[k] = (unsigned short)f2bf(v[k]);
      *(u16x8*)&Sl[n * LDST + m0] = o;            // 16-B aligned
    }
  }
  __syncthreads();

  const unsigned short* qt0 = &Qt[(i0 + ln) * LDQT];        // tile 0 row
  const unsigned short* qt1 = &Qt[(64 + i0 + ln) * LDQT];   // tile 1 row
  const unsigned short* slb = &Sl[(j0 + ln) * LDST];        // S^T row j

  f32x16 acc0, acc1;
  #pragma unroll
  for (int r = 0; r < 16; ++r) { acc0[r] = 0.f; acc1[r] = 0.f; }

  #pragma unroll
  for (int kc = 0; kc < 3; ++kc) {       // m0 <= 47: all fragment m's valid
    const int m0 = kc * 16 + g * 8;
    const bf16x8 a0 = *(const bf16x8*)&qt0[m0];    // one ds_read_b128
    const bf16x8 a1 = *(const bf16x8*)&qt1[m0];
    const bf16x8 bh = *(const bf16x8*)&slb[m0];
    acc0 = __builtin_amdgcn_mfma_f32_32x32x16_bf16(a0, bh, acc0, 0, 0, 0);
    acc1 = __builtin_amdgcn_mfma_f32_32x32x16_bf16(a1, bh, acc1, 0, 0, 0);
  }
  {                                      // tail: only m=48 real; S cols m>=49
    const int m0 = 48 + g * 8;           // are finite junk -> 0*finite = 0
    bf16x8 a0, a1;
    #pragma unroll
    for (int e = 0; e < 8; ++e) { a0[e] = 0; a1[e] = 0; }
    a0[0] = (g == 0) ? (short)qt0[48] : (short)0;
    a1[0] = (g == 0) ? (short)qt1[48] : (short)0;
    const bf16x8 bh = *(const bf16x8*)&slb[m0];
    acc0 = __builtin_amdgcn_mfma_f32_32x32x16_bf16(a0, bh, acc0, 0, 0, 0);
    acc1 = __builtin_amdgcn_mfma_f32_32x32x16_bf16(a1, bh, acc1, 0, 0, 0);
  }

  // epilogue: all 64 rows/tile valid; guard col j < 49; coalesced per r
  const int j = j0 + ln;
  if (j < NN) {
    #pragma unroll
    for (int r = 0; r < 16; ++r) {
      const int i = i0 + (r & 3) + 8 * (r >> 2) + 4 * g;
      const size_t o0 = qbase + (size_t)i * NN + j;
      const size_t o1 = qbase + (size_t)(64 + i) * NN + j;
      Og[o0] = acc0[r] + Vg[o0];
      Og[o1] = acc1[r] + Vg[o1];
    }
  }
}

extern "C" void kernel_launch(void* const* d_in, const int* in_sizes, int n_in,
                              void* d_out, int out_size, void* d_ws, size_t ws_size,
                              hipStream_t stream) {
  (void)in_sizes; (void)n_in; (void)out_size; (void)ws_size;
  const float* v1 = (const float*)d_in[0];
  const float* q1 = (const float*)d_in[1];
  const float* k1 = (const float*)d_in[2];
  float* out = (float*)d_out;

  unsigned short* spart = (unsigned short*)d_ws;   // 1024 * 6272 B = 6.42 MB

  ktv_kernel<<<dim3(BATCH * SPLIT), dim3(256), 0, stream>>>(k1, v1, spart);
  qs_kernel<<<dim3(BATCH * 8), dim3(256), 0, stream>>>(q1, v1, spart, out);
}